// Round 1
// baseline (566.015 us; speedup 1.0000x reference)
//
#include <hip/hip_runtime.h>
#include <hip/hip_bf16.h>

#define CCH 256
#define CQK 32
#define NHW 4096

typedef float f32x4 __attribute__((ext_vector_type(4)));
typedef _Float16 hv8 __attribute__((ext_vector_type(8)));

// ---------------------------------------------------------------------------
// Projection kernel: b = b_w@a+b_b (32ch), c = c_w@a+c_b (32ch), d = d_w@a+d_b
// (256ch). Writes q/k transposed ([n][pos][32] fp16) so attention A/B fragment
// loads are single 16B loads; writes v natural ([n][ch][pos] fp16).
// Grid: 4 batches x 64 position-tiles of 64. Block: 256 threads.
// ---------------------------------------------------------------------------
__global__ __launch_bounds__(256) void proj_kernel(
    const float* __restrict__ a,
    const float* __restrict__ b_w, const float* __restrict__ b_b,
    const float* __restrict__ c_w, const float* __restrict__ c_b,
    const float* __restrict__ d_w, const float* __restrict__ d_b,
    _Float16* __restrict__ bqT, _Float16* __restrict__ ckT,
    _Float16* __restrict__ dv)
{
    __shared__ float at[CCH][64];   // 64 KB: a[n, :, i0:i0+64]
    const int n   = blockIdx.x >> 6;
    const int i0  = (blockIdx.x & 63) << 6;
    const int tid = threadIdx.x;

    #pragma unroll
    for (int k = 0; k < 16; ++k) {
        int idx = tid + (k << 8);
        int c = idx >> 4, f4 = (idx & 15) << 2;
        *reinterpret_cast<float4*>(&at[c][f4]) =
            *reinterpret_cast<const float4*>(a + (size_t)(n * CCH + c) * NHW + i0 + f4);
    }
    __syncthreads();

    const int i_loc = tid & 63;
    const int g     = tid >> 6;     // 0..3: channel-group split across waves
    const int q     = i0 + i_loc;

    // b,c projections: 8 channels each per group
    {
        float accb[8], accc[8];
        #pragma unroll
        for (int j = 0; j < 8; ++j) { accb[j] = b_b[g*8 + j]; accc[j] = c_b[g*8 + j]; }
        for (int c = 0; c < CCH; c += 4) {
            float av0 = at[c+0][i_loc], av1 = at[c+1][i_loc];
            float av2 = at[c+2][i_loc], av3 = at[c+3][i_loc];
            #pragma unroll
            for (int j = 0; j < 8; ++j) {
                float4 wb = *reinterpret_cast<const float4*>(b_w + (g*8 + j)*CCH + c);
                float4 wc = *reinterpret_cast<const float4*>(c_w + (g*8 + j)*CCH + c);
                accb[j] = fmaf(wb.x, av0, accb[j]); accb[j] = fmaf(wb.y, av1, accb[j]);
                accb[j] = fmaf(wb.z, av2, accb[j]); accb[j] = fmaf(wb.w, av3, accb[j]);
                accc[j] = fmaf(wc.x, av0, accc[j]); accc[j] = fmaf(wc.y, av1, accc[j]);
                accc[j] = fmaf(wc.z, av2, accc[j]); accc[j] = fmaf(wc.w, av3, accc[j]);
            }
        }
        #pragma unroll
        for (int j = 0; j < 8; ++j) {
            bqT[((size_t)n*NHW + q)*CQK + g*8 + j] = (_Float16)accb[j];
            ckT[((size_t)n*NHW + q)*CQK + g*8 + j] = (_Float16)accc[j];
        }
    }

    // d projection: 64 channels per group, 8 at a time
    for (int ob = 0; ob < 8; ++ob) {
        int obase = g*64 + ob*8;
        float acc[8];
        #pragma unroll
        for (int j = 0; j < 8; ++j) acc[j] = d_b[obase + j];
        for (int c = 0; c < CCH; c += 4) {
            float av0 = at[c+0][i_loc], av1 = at[c+1][i_loc];
            float av2 = at[c+2][i_loc], av3 = at[c+3][i_loc];
            #pragma unroll
            for (int j = 0; j < 8; ++j) {
                float4 wd = *reinterpret_cast<const float4*>(d_w + (obase + j)*CCH + c);
                acc[j] = fmaf(wd.x, av0, acc[j]); acc[j] = fmaf(wd.y, av1, acc[j]);
                acc[j] = fmaf(wd.z, av2, acc[j]); acc[j] = fmaf(wd.w, av3, acc[j]);
            }
        }
        #pragma unroll
        for (int j = 0; j < 8; ++j)
            dv[((size_t)n*CCH + obase + j)*NHW + i0 + i_loc] = (_Float16)acc[j];
    }
}

// ---------------------------------------------------------------------------
// Flash attention kernel. Grid: 4 batches x 64 query-tiles of TQ=64.
// Block: 256 threads = 4 waves; each wave owns 16 query rows.
// KV loop over 64 key-tiles of TK=64. Online softmax per wave (state for its
// 16 rows lives per-quad-duplicated in registers).
// Layout facts used (guide-verified, dtype-independent):
//   mfma_f32_16x16x32: C/D col=lane&15, row=quad*4+reg
//                      A[m=lane&15][k=quad*8+j], B[k=quad*8+j][n=lane&15]
// ---------------------------------------------------------------------------
__global__ __launch_bounds__(256) void attn_kernel(
    const _Float16* __restrict__ bqT, const _Float16* __restrict__ ckT,
    const _Float16* __restrict__ dv, const float* __restrict__ a,
    const float* __restrict__ alpha_p, float* __restrict__ out)
{
    __shared__ _Float16 dv_lds[CCH * 72];    // v tile [256co][64k], +8 pad -> 2-way max
    __shared__ _Float16 p_lds[4][16 * 72];   // per-wave P round-trip, +8 pad
    __shared__ float    trans[64 * 68];      // epilogue transpose, +4 pad (16B aligned)

    const int n    = blockIdx.x >> 6;
    const int q0   = (blockIdx.x & 63) << 6;
    const int tid  = threadIdx.x;
    const int wave = tid >> 6;
    const int lane = tid & 63;
    const int l15  = lane & 15;
    const int quad = lane >> 4;

    const f32x4 zf = {0.f, 0.f, 0.f, 0.f};

    // Q fragment: rows m = l15 -> q = q0 + wave*16 + l15; k-dim = channel quad*8+j
    const hv8 qf = *reinterpret_cast<const hv8*>(
        bqT + ((size_t)n*NHW + q0 + wave*16 + l15)*CQK + quad*8);

    f32x4 acc[16];
    #pragma unroll
    for (int t = 0; t < 16; ++t) acc[t] = zf;
    float m_r[4] = {-1e30f, -1e30f, -1e30f, -1e30f};
    float l_r[4] = {0.f, 0.f, 0.f, 0.f};

    const int co_s = tid >> 3;
    const int c8_s = (tid & 7) << 3;

    for (int kt = 0; kt < 64; ++kt) {
        const int k0 = kt << 6;
        __syncthreads();   // protect dv_lds from previous iteration's readers
        #pragma unroll
        for (int p = 0; p < 8; ++p) {
            int co = co_s + (p << 5);
            *reinterpret_cast<int4*>(&dv_lds[co*72 + c8_s]) =
                *reinterpret_cast<const int4*>(dv + ((size_t)n*CCH + co)*NHW + k0 + c8_s);
        }
        __syncthreads();

        // ---- S = Q K^T : 4 MFMAs cover keys k0..k0+63, full 32-ch reduction
        f32x4 s[4];
        #pragma unroll
        for (int f = 0; f < 4; ++f) {
            hv8 kf = *reinterpret_cast<const hv8*>(
                ckT + ((size_t)n*NHW + k0 + f*16 + l15)*CQK + quad*8);
            s[f] = __builtin_amdgcn_mfma_f32_16x16x32_f16(qf, kf, zf, 0, 0, 0);
        }

        // ---- online softmax for this wave's 16 rows (row = quad*4 + r)
        float mx[4], alp[4], rowsum[4];
        #pragma unroll
        for (int r = 0; r < 4; ++r) {
            float v = fmaxf(fmaxf(s[0][r], s[1][r]), fmaxf(s[2][r], s[3][r]));
            v = fmaxf(v, __shfl_xor(v, 1, 64));
            v = fmaxf(v, __shfl_xor(v, 2, 64));
            v = fmaxf(v, __shfl_xor(v, 4, 64));
            v = fmaxf(v, __shfl_xor(v, 8, 64));
            mx[r] = v;
        }
        #pragma unroll
        for (int r = 0; r < 4; ++r) {
            float mn = fmaxf(m_r[r], mx[r]);
            alp[r] = __expf(m_r[r] - mn);
            m_r[r] = mn;
            rowsum[r] = 0.f;
        }
        #pragma unroll
        for (int f = 0; f < 4; ++f) {
            #pragma unroll
            for (int r = 0; r < 4; ++r) {
                float p = __expf(s[f][r] - m_r[r]);
                rowsum[r] += p;
                p_lds[wave][(quad*4 + r)*72 + f*16 + l15] = (_Float16)p;
            }
        }
        #pragma unroll
        for (int r = 0; r < 4; ++r) {
            float v = rowsum[r];
            v += __shfl_xor(v, 1, 64);
            v += __shfl_xor(v, 2, 64);
            v += __shfl_xor(v, 4, 64);
            v += __shfl_xor(v, 8, 64);
            l_r[r] = l_r[r]*alp[r] + v;
        }
        #pragma unroll
        for (int t = 0; t < 16; ++t) {
            #pragma unroll
            for (int r = 0; r < 4; ++r) acc[t][r] *= alp[r];
        }

        // ---- P: C/D layout -> A layout via per-wave LDS round-trip
        hv8 pf0 = *reinterpret_cast<const hv8*>(&p_lds[wave][l15*72 + quad*8]);
        hv8 pf1 = *reinterpret_cast<const hv8*>(&p_lds[wave][l15*72 + 32 + quad*8]);

        // ---- O += P V^T : 16 co-frags x 2 key-halves
        #pragma unroll
        for (int t = 0; t < 16; ++t) {
            hv8 d0 = *reinterpret_cast<const hv8*>(&dv_lds[(t*16 + l15)*72 + quad*8]);
            acc[t] = __builtin_amdgcn_mfma_f32_16x16x32_f16(pf0, d0, acc[t], 0, 0, 0);
            hv8 d1 = *reinterpret_cast<const hv8*>(&dv_lds[(t*16 + l15)*72 + 32 + quad*8]);
            acc[t] = __builtin_amdgcn_mfma_f32_16x16x32_f16(pf1, d1, acc[t], 0, 0, 0);
        }
    }

    // ---- epilogue: out = alpha * O/l + a, transposed to [co][q] via LDS
    const float alpha = alpha_p[0];
    float rl[4];
    #pragma unroll
    for (int r = 0; r < 4; ++r) rl[r] = alpha / l_r[r];

    #pragma unroll
    for (int p = 0; p < 4; ++p) {
        __syncthreads();
        #pragma unroll
        for (int t4 = 0; t4 < 4; ++t4) {
            int t = p*4 + t4;
            #pragma unroll
            for (int r = 0; r < 4; ++r)
                trans[(t4*16 + l15)*68 + wave*16 + quad*4 + r] = acc[t][r] * rl[r];
        }
        __syncthreads();
        #pragma unroll
        for (int it = 0; it < 4; ++it) {
            int row = it*16 + (tid >> 4);
            int col = (tid & 15) << 2;
            int co  = p*64 + row;
            float4 v  = *reinterpret_cast<const float4*>(&trans[row*68 + col]);
            float4 av = *reinterpret_cast<const float4*>(
                a + ((size_t)n*CCH + co)*NHW + q0 + col);
            float4 o;
            o.x = v.x + av.x; o.y = v.y + av.y; o.z = v.z + av.z; o.w = v.w + av.w;
            *reinterpret_cast<float4*>(out + ((size_t)n*CCH + co)*NHW + q0 + col) = o;
        }
    }
}

extern "C" void kernel_launch(void* const* d_in, const int* in_sizes, int n_in,
                              void* d_out, int out_size, void* d_ws, size_t ws_size,
                              hipStream_t stream)
{
    const float* a    = (const float*)d_in[0];
    const float* b_w  = (const float*)d_in[1];
    const float* b_b  = (const float*)d_in[2];
    const float* c_w  = (const float*)d_in[3];
    const float* c_b  = (const float*)d_in[4];
    const float* d_w  = (const float*)d_in[5];
    const float* d_b  = (const float*)d_in[6];
    const float* alp  = (const float*)d_in[7];
    float* out = (float*)d_out;

    _Float16* bqT = (_Float16*)d_ws;                  // [4][4096][32] fp16, 1 MB
    _Float16* ckT = bqT + (size_t)4*NHW*CQK;          // [4][4096][32] fp16, 1 MB
    _Float16* dv  = ckT + (size_t)4*NHW*CQK;          // [4][256][4096] fp16, 8 MB

    proj_kernel<<<256, 256, 0, stream>>>(a, b_w, b_b, c_w, c_b, d_w, d_b, bqT, ckT, dv);
    attn_kernel<<<256, 256, 0, stream>>>(bqT, ckT, dv, a, alp, out);
}

// Round 3
// 437.356 us; speedup vs baseline: 1.2942x; 1.2942x over previous
//
#include <hip/hip_runtime.h>
#include <hip/hip_bf16.h>

#define CCH 256
#define CQK 32
#define NHW 4096

typedef float f32x4 __attribute__((ext_vector_type(4)));
typedef _Float16 hv8 __attribute__((ext_vector_type(8)));

// ---------------------------------------------------------------------------
// Projection kernel (round-1 verified VALU structure).
// Grid: 1024 = 4 work-variants x 4 batches x 64 position-tiles of 64.
// Variant v=0: b,c projections + d-channels obs {0,1}; v=1..3: d-obs {2v,2v+1}.
// a-tile staged in LDS as fp16 (37 KB -> 4 blocks/CU).
// ---------------------------------------------------------------------------
__global__ __launch_bounds__(256) void proj_kernel(
    const float* __restrict__ a,
    const float* __restrict__ b_w, const float* __restrict__ b_b,
    const float* __restrict__ c_w, const float* __restrict__ c_b,
    const float* __restrict__ d_w, const float* __restrict__ d_b,
    _Float16* __restrict__ bqT, _Float16* __restrict__ ckT,
    _Float16* __restrict__ dv)
{
    __shared__ _Float16 at[CCH][72];   // [ch][pos], 36.9 KB
    const int bx  = blockIdx.x;
    const int v   = bx >> 8;                 // 0..3 work split
    const int n   = (bx >> 6) & 3;
    const int i0  = (bx & 63) << 6;
    const int tid = threadIdx.x;

    #pragma unroll
    for (int k = 0; k < 16; ++k) {
        int idx = tid + (k << 8);
        int c = idx >> 4, f4 = (idx & 15) << 2;
        float4 w = *reinterpret_cast<const float4*>(
            a + (size_t)(n * CCH + c) * NHW + i0 + f4);
        at[c][f4 + 0] = (_Float16)w.x;
        at[c][f4 + 1] = (_Float16)w.y;
        at[c][f4 + 2] = (_Float16)w.z;
        at[c][f4 + 3] = (_Float16)w.w;
    }
    __syncthreads();

    const int i_loc = tid & 63;
    const int g     = tid >> 6;     // 0..3: channel-group split across waves
    const int q     = i0 + i_loc;

    if (v == 0) {
        // b,c projections: 8 channels each per group
        float accb[8], accc[8];
        #pragma unroll
        for (int j = 0; j < 8; ++j) { accb[j] = b_b[g*8 + j]; accc[j] = c_b[g*8 + j]; }
        for (int c = 0; c < CCH; c += 4) {
            float av0 = (float)at[c+0][i_loc], av1 = (float)at[c+1][i_loc];
            float av2 = (float)at[c+2][i_loc], av3 = (float)at[c+3][i_loc];
            #pragma unroll
            for (int j = 0; j < 8; ++j) {
                float4 wb = *reinterpret_cast<const float4*>(b_w + (g*8 + j)*CCH + c);
                float4 wc = *reinterpret_cast<const float4*>(c_w + (g*8 + j)*CCH + c);
                accb[j] = fmaf(wb.x, av0, accb[j]); accb[j] = fmaf(wb.y, av1, accb[j]);
                accb[j] = fmaf(wb.z, av2, accb[j]); accb[j] = fmaf(wb.w, av3, accb[j]);
                accc[j] = fmaf(wc.x, av0, accc[j]); accc[j] = fmaf(wc.y, av1, accc[j]);
                accc[j] = fmaf(wc.z, av2, accc[j]); accc[j] = fmaf(wc.w, av3, accc[j]);
            }
        }
        #pragma unroll
        for (int j = 0; j < 8; ++j) {
            bqT[((size_t)n*NHW + q)*CQK + g*8 + j] = (_Float16)accb[j];
            ckT[((size_t)n*NHW + q)*CQK + g*8 + j] = (_Float16)accc[j];
        }
    }

    // d projection: this variant's 2 ob-slots (16 channels per group)
    for (int ob = v*2; ob < v*2 + 2; ++ob) {
        int obase = g*64 + ob*8;
        float acc[8];
        #pragma unroll
        for (int j = 0; j < 8; ++j) acc[j] = d_b[obase + j];
        for (int c = 0; c < CCH; c += 4) {
            float av0 = (float)at[c+0][i_loc], av1 = (float)at[c+1][i_loc];
            float av2 = (float)at[c+2][i_loc], av3 = (float)at[c+3][i_loc];
            #pragma unroll
            for (int j = 0; j < 8; ++j) {
                float4 wd = *reinterpret_cast<const float4*>(d_w + (obase + j)*CCH + c);
                acc[j] = fmaf(wd.x, av0, acc[j]); acc[j] = fmaf(wd.y, av1, acc[j]);
                acc[j] = fmaf(wd.z, av2, acc[j]); acc[j] = fmaf(wd.w, av3, acc[j]);
            }
        }
        #pragma unroll
        for (int j = 0; j < 8; ++j)
            dv[((size_t)n*CCH + obase + j)*NHW + i0 + i_loc] = (_Float16)acc[j];
    }
}

// ---------------------------------------------------------------------------
// Flash attention (round-1 verified inner loop; co-split grid).
// Grid: 4n x 4 co-groups x 64 q-tiles = 1024. Block 256 = 4 waves; wave w owns
// q-rows q0+16w..+15 for all 64 co of its group. Straight PV: acc = O[q][co]
// (row=quad*4+r -> q, col=l15 -> co). Single-pass trans epilogue.
// ---------------------------------------------------------------------------
__global__ __launch_bounds__(256) void attn_kernel(
    const _Float16* __restrict__ bqT, const _Float16* __restrict__ ckT,
    const _Float16* __restrict__ dv, const float* __restrict__ a,
    const float* __restrict__ alpha_p, float* __restrict__ out)
{
    __shared__ _Float16 dv_lds[64 * 72];     // V tile [64co][64k]+8 pad
    __shared__ _Float16 p_lds[4][16 * 72];   // per-wave P round-trip
    __shared__ float    trans[64 * 68];      // epilogue transpose

    const int bx   = blockIdx.x;
    const int n    = bx >> 8;
    const int cg   = (bx >> 6) & 3;
    const int q0   = (bx & 63) << 6;
    const int co0  = cg << 6;
    const int tid  = threadIdx.x;
    const int wave = tid >> 6;
    const int lane = tid & 63;
    const int l15  = lane & 15;
    const int quad = lane >> 4;

    const f32x4 zf = {0.f, 0.f, 0.f, 0.f};

    const hv8 qf = *reinterpret_cast<const hv8*>(
        bqT + ((size_t)n*NHW + q0 + wave*16 + l15)*CQK + quad*8);

    f32x4 acc[4];
    #pragma unroll
    for (int t = 0; t < 4; ++t) acc[t] = zf;
    float m_r[4] = {-1e30f, -1e30f, -1e30f, -1e30f};
    float l_r[4] = {0.f, 0.f, 0.f, 0.f};

    const int co_s = tid >> 3;          // 0..31
    const int c8_s = (tid & 7) << 3;    // 0..56

    for (int kt = 0; kt < 64; ++kt) {
        const int k0 = kt << 6;
        __syncthreads();   // previous iteration's dv_lds readers done
        #pragma unroll
        for (int p = 0; p < 2; ++p) {
            int co = co_s + (p << 5);
            *reinterpret_cast<int4*>(&dv_lds[co*72 + c8_s]) =
                *reinterpret_cast<const int4*>(
                    dv + ((size_t)n*CCH + co0 + co)*NHW + k0 + c8_s);
        }
        __syncthreads();

        // ---- S = Q K^T (C/D: row=quad*4+r -> q, col=l15 -> key)
        f32x4 s[4];
        #pragma unroll
        for (int f = 0; f < 4; ++f) {
            hv8 kf = *reinterpret_cast<const hv8*>(
                ckT + ((size_t)n*NHW + k0 + f*16 + l15)*CQK + quad*8);
            s[f] = __builtin_amdgcn_mfma_f32_16x16x32_f16(qf, kf, zf, 0, 0, 0);
        }

        // ---- online softmax for this wave's 16 rows
        float mx[4], alp[4], rowsum[4];
        #pragma unroll
        for (int r = 0; r < 4; ++r) {
            float v = fmaxf(fmaxf(s[0][r], s[1][r]), fmaxf(s[2][r], s[3][r]));
            v = fmaxf(v, __shfl_xor(v, 1, 64));
            v = fmaxf(v, __shfl_xor(v, 2, 64));
            v = fmaxf(v, __shfl_xor(v, 4, 64));
            v = fmaxf(v, __shfl_xor(v, 8, 64));
            mx[r] = v;
        }
        #pragma unroll
        for (int r = 0; r < 4; ++r) {
            float mn = fmaxf(m_r[r], mx[r]);
            alp[r] = __expf(m_r[r] - mn);
            m_r[r] = mn;
            rowsum[r] = 0.f;
        }
        #pragma unroll
        for (int f = 0; f < 4; ++f) {
            #pragma unroll
            for (int r = 0; r < 4; ++r) {
                float p = __expf(s[f][r] - m_r[r]);
                rowsum[r] += p;
                p_lds[wave][(quad*4 + r)*72 + f*16 + l15] = (_Float16)p;
            }
        }
        #pragma unroll
        for (int r = 0; r < 4; ++r) {
            float v = rowsum[r];
            v += __shfl_xor(v, 1, 64);
            v += __shfl_xor(v, 2, 64);
            v += __shfl_xor(v, 4, 64);
            v += __shfl_xor(v, 8, 64);
            l_r[r] = l_r[r]*alp[r] + v;
        }
        #pragma unroll
        for (int t = 0; t < 4; ++t) {
            #pragma unroll
            for (int r = 0; r < 4; ++r) acc[t][r] *= alp[r];
        }

        // ---- P: C/D layout -> A layout via per-wave LDS round-trip
        hv8 pf0 = *reinterpret_cast<const hv8*>(&p_lds[wave][l15*72 + quad*8]);
        hv8 pf1 = *reinterpret_cast<const hv8*>(&p_lds[wave][l15*72 + 32 + quad*8]);

        // ---- O[q][co] += P V^T : 4 co-frags x 2 key-halves
        #pragma unroll
        for (int t = 0; t < 4; ++t) {
            hv8 d0 = *reinterpret_cast<const hv8*>(&dv_lds[(t*16 + l15)*72 + quad*8]);
            acc[t] = __builtin_amdgcn_mfma_f32_16x16x32_f16(pf0, d0, acc[t], 0, 0, 0);
            hv8 d1 = *reinterpret_cast<const hv8*>(&dv_lds[(t*16 + l15)*72 + 32 + quad*8]);
            acc[t] = __builtin_amdgcn_mfma_f32_16x16x32_f16(pf1, d1, acc[t], 0, 0, 0);
        }
    }

    // ---- epilogue: out = alpha * O/l + a, transposed to [co][q] via LDS
    const float alpha = alpha_p[0];
    float rl[4];
    #pragma unroll
    for (int r = 0; r < 4; ++r) rl[r] = alpha / l_r[r];

    __syncthreads();
    #pragma unroll
    for (int t = 0; t < 4; ++t) {
        #pragma unroll
        for (int r = 0; r < 4; ++r)
            trans[(t*16 + l15)*68 + wave*16 + quad*4 + r] = acc[t][r] * rl[r];
    }
    __syncthreads();
    #pragma unroll
    for (int it = 0; it < 4; ++it) {
        int row = it*16 + (tid >> 4);
        int col = (tid & 15) << 2;
        int co  = co0 + row;
        float4 v  = *reinterpret_cast<const float4*>(&trans[row*68 + col]);
        float4 av = *reinterpret_cast<const float4*>(
            a + ((size_t)n*CCH + co)*NHW + q0 + col);
        float4 o;
        o.x = v.x + av.x; o.y = v.y + av.y; o.z = v.z + av.z; o.w = v.w + av.w;
        *reinterpret_cast<float4*>(out + ((size_t)n*CCH + co)*NHW + q0 + col) = o;
    }
}

extern "C" void kernel_launch(void* const* d_in, const int* in_sizes, int n_in,
                              void* d_out, int out_size, void* d_ws, size_t ws_size,
                              hipStream_t stream)
{
    const float* a    = (const float*)d_in[0];
    const float* b_w  = (const float*)d_in[1];
    const float* b_b  = (const float*)d_in[2];
    const float* c_w  = (const float*)d_in[3];
    const float* c_b  = (const float*)d_in[4];
    const float* d_w  = (const float*)d_in[5];
    const float* d_b  = (const float*)d_in[6];
    const float* alp  = (const float*)d_in[7];
    float* out = (float*)d_out;

    _Float16* bqT = (_Float16*)d_ws;                  // [4][4096][32] fp16, 1 MB
    _Float16* ckT = bqT + (size_t)4*NHW*CQK;          // [4][4096][32] fp16, 1 MB
    _Float16* dv  = ckT + (size_t)4*NHW*CQK;          // [4][256][4096] fp16, 8 MB

    proj_kernel<<<1024, 256, 0, stream>>>(a, b_w, b_b, c_w, c_b, d_w, d_b, bqT, ckT, dv);
    attn_kernel<<<1024, 256, 0, stream>>>(bqT, ckT, dv, a, alp, out);
}

// Round 4
// 293.050 us; speedup vs baseline: 1.9315x; 1.4924x over previous
//
#include <hip/hip_runtime.h>
#include <hip/hip_bf16.h>

#define CCH 256
#define CQK 32
#define NHW 4096

typedef float f32x4 __attribute__((ext_vector_type(4)));
typedef _Float16 hv8 __attribute__((ext_vector_type(8)));

// ---------------------------------------------------------------------------
// Projection kernel (MFMA): out[320][pos] = Wall[320][256] @ a[256][pos] + bias
// Wall = concat(b_w 32, c_w 32, d_w 256), converted fp32->fp16 in-register.
// Grid: 4 batches x 128 position-tiles of 32. Block 256 = 4 waves; wave w owns
// out-channels 80w..80w+79 (5 m-frags) x 32 positions (2 n-frags).
// a-tile staged transposed in LDS as fp16 so B-frags are contiguous 16B reads.
// LDS row stride = CCH+24 = 280 halves = 560 B: multiple of 16 (ds_read_b128
// alignment — round-2's 528 B stride was the bug) and 140 dwords = 12 mod 32
// banks -> at most 2-way conflicts (free).
// ---------------------------------------------------------------------------
__global__ __launch_bounds__(256) void proj_kernel(
    const float* __restrict__ a,
    const float* __restrict__ b_w, const float* __restrict__ b_b,
    const float* __restrict__ c_w, const float* __restrict__ c_b,
    const float* __restrict__ d_w, const float* __restrict__ d_b,
    _Float16* __restrict__ bqT, _Float16* __restrict__ ckT,
    _Float16* __restrict__ dv)
{
    __shared__ _Float16 aT[32][CCH + 24];   // [pos][ch] fp16, ~17.9 KB

    const int n    = blockIdx.x >> 7;
    const int i0   = (blockIdx.x & 127) << 5;
    const int tid  = threadIdx.x;
    const int lane = tid & 63;
    const int wave = tid >> 6;
    const int l15  = lane & 15;
    const int quad = lane >> 4;

    // stage a^T tile: thread handles channel c = tid, 32 positions
    {
        const float* ap = a + (size_t)(n*CCH + tid)*NHW + i0;
        #pragma unroll
        for (int j = 0; j < 8; ++j) {
            float4 v = *reinterpret_cast<const float4*>(ap + j*4);
            aT[j*4+0][tid] = (_Float16)v.x;
            aT[j*4+1][tid] = (_Float16)v.y;
            aT[j*4+2][tid] = (_Float16)v.z;
            aT[j*4+3][tid] = (_Float16)v.w;
        }
    }
    __syncthreads();

    const f32x4 zf = {0.f, 0.f, 0.f, 0.f};
    f32x4 acc[5][2];
    #pragma unroll
    for (int t = 0; t < 5; ++t) { acc[t][0] = zf; acc[t][1] = zf; }

    const int ch0w = wave * 80;

    #pragma unroll
    for (int ks = 0; ks < 8; ++ks) {
        const int k0 = ks * 32;
        hv8 bf0 = *reinterpret_cast<const hv8*>(&aT[l15][k0 + quad*8]);
        hv8 bf1 = *reinterpret_cast<const hv8*>(&aT[16 + l15][k0 + quad*8]);
        #pragma unroll
        for (int t = 0; t < 5; ++t) {
            const int ch0 = ch0w + t*16;
            const float* wbase = (ch0 < 32) ? (b_w + ch0*CCH)
                               : (ch0 < 64) ? (c_w + (ch0-32)*CCH)
                                            : (d_w + (ch0-64)*CCH);
            const float* wp = wbase + l15*CCH + k0 + quad*8;
            float4 w0 = *reinterpret_cast<const float4*>(wp);
            float4 w1 = *reinterpret_cast<const float4*>(wp + 4);
            hv8 af = { (_Float16)w0.x, (_Float16)w0.y, (_Float16)w0.z, (_Float16)w0.w,
                       (_Float16)w1.x, (_Float16)w1.y, (_Float16)w1.z, (_Float16)w1.w };
            acc[t][0] = __builtin_amdgcn_mfma_f32_16x16x32_f16(af, bf0, acc[t][0], 0, 0, 0);
            acc[t][1] = __builtin_amdgcn_mfma_f32_16x16x32_f16(af, bf1, acc[t][1], 0, 0, 0);
        }
    }

    // epilogue: C/D layout row = quad*4+r (out-ch), col = l15 (pos)
    #pragma unroll
    for (int t = 0; t < 5; ++t) {
        const int ch0 = ch0w + t*16;
        if (ch0 < 64) {
            const float* bias_arr = (ch0 < 32) ? b_b : c_b;
            _Float16*    outp     = (ch0 < 32) ? bqT : ckT;
            const int    chl      = ch0 & 31;
            #pragma unroll
            for (int r = 0; r < 4; ++r) {
                const int ch_in = chl + quad*4 + r;
                const float bias = bias_arr[ch_in];
                #pragma unroll
                for (int nf = 0; nf < 2; ++nf) {
                    const int pos = i0 + nf*16 + l15;
                    outp[((size_t)n*NHW + pos)*CQK + ch_in] =
                        (_Float16)(acc[t][nf][r] + bias);
                }
            }
        } else {
            const int chd = ch0 - 64;
            #pragma unroll
            for (int r = 0; r < 4; ++r) {
                const int ch = chd + quad*4 + r;
                const float bias = d_b[ch];
                #pragma unroll
                for (int nf = 0; nf < 2; ++nf) {
                    const int pos = i0 + nf*16 + l15;
                    dv[((size_t)n*CCH + ch)*NHW + pos] =
                        (_Float16)(acc[t][nf][r] + bias);
                }
            }
        }
    }
}

// ---------------------------------------------------------------------------
// Flash attention (round-3 verified structure + ones-column denominator).
// Grid: 4n x 4 co-groups x 64 q-tiles = 1024. Block 256 = 4 waves; wave w owns
// q-rows q0+16w..+15 for all 64 co of its group. Straight PV: acc = O[q][co]
// (row=quad*4+r -> q, col=l15 -> co).
// Softmax denominator l is accumulated as an extra MFMA accumulator:
// acc_l = mfma(P_frag, ONES, acc_l), rescaled by alp exactly like acc — this
// is exact (same rescale chain) and deletes the per-iter sum shuffle-reduce.
// ---------------------------------------------------------------------------
__global__ __launch_bounds__(256) void attn_kernel(
    const _Float16* __restrict__ bqT, const _Float16* __restrict__ ckT,
    const _Float16* __restrict__ dv, const float* __restrict__ a,
    const float* __restrict__ alpha_p, float* __restrict__ out)
{
    __shared__ _Float16 dv_lds[64 * 72];     // V tile [64co][64k]+8 pad
    __shared__ _Float16 p_lds[4][16 * 72];   // per-wave P round-trip
    __shared__ float    trans[64 * 68];      // epilogue transpose

    const int bx   = blockIdx.x;
    const int n    = bx >> 8;
    const int cg   = (bx >> 6) & 3;
    const int q0   = (bx & 63) << 6;
    const int co0  = cg << 6;
    const int tid  = threadIdx.x;
    const int wave = tid >> 6;
    const int lane = tid & 63;
    const int l15  = lane & 15;
    const int quad = lane >> 4;

    const f32x4 zf = {0.f, 0.f, 0.f, 0.f};
    const _Float16 one_h = (_Float16)1.0f;
    const hv8 ones = { one_h, one_h, one_h, one_h, one_h, one_h, one_h, one_h };

    const hv8 qf = *reinterpret_cast<const hv8*>(
        bqT + ((size_t)n*NHW + q0 + wave*16 + l15)*CQK + quad*8);

    f32x4 acc[4];
    #pragma unroll
    for (int t = 0; t < 4; ++t) acc[t] = zf;
    f32x4 acc_l = zf;                       // softmax denominator per q-row
    float m_r[4] = {-1e30f, -1e30f, -1e30f, -1e30f};

    const int co_s = tid >> 3;          // 0..31
    const int c8_s = (tid & 7) << 3;    // 0..56

    for (int kt = 0; kt < 64; ++kt) {
        const int k0 = kt << 6;
        __syncthreads();   // previous iteration's dv_lds readers done
        #pragma unroll
        for (int p = 0; p < 2; ++p) {
            int co = co_s + (p << 5);
            *reinterpret_cast<int4*>(&dv_lds[co*72 + c8_s]) =
                *reinterpret_cast<const int4*>(
                    dv + ((size_t)n*CCH + co0 + co)*NHW + k0 + c8_s);
        }
        __syncthreads();

        // ---- S = Q K^T (C/D: row=quad*4+r -> q, col=l15 -> key)
        f32x4 s[4];
        #pragma unroll
        for (int f = 0; f < 4; ++f) {
            hv8 kf = *reinterpret_cast<const hv8*>(
                ckT + ((size_t)n*NHW + k0 + f*16 + l15)*CQK + quad*8);
            s[f] = __builtin_amdgcn_mfma_f32_16x16x32_f16(qf, kf, zf, 0, 0, 0);
        }

        // ---- online softmax max-update for this wave's 16 rows
        float alp[4];
        #pragma unroll
        for (int r = 0; r < 4; ++r) {
            float v = fmaxf(fmaxf(s[0][r], s[1][r]), fmaxf(s[2][r], s[3][r]));
            v = fmaxf(v, __shfl_xor(v, 1, 64));
            v = fmaxf(v, __shfl_xor(v, 2, 64));
            v = fmaxf(v, __shfl_xor(v, 4, 64));
            v = fmaxf(v, __shfl_xor(v, 8, 64));
            float mn = fmaxf(m_r[r], v);
            alp[r] = __expf(m_r[r] - mn);
            m_r[r] = mn;
        }
        #pragma unroll
        for (int f = 0; f < 4; ++f) {
            #pragma unroll
            for (int r = 0; r < 4; ++r) {
                float p = __expf(s[f][r] - m_r[r]);
                p_lds[wave][(quad*4 + r)*72 + f*16 + l15] = (_Float16)p;
            }
        }
        #pragma unroll
        for (int t = 0; t < 4; ++t) {
            #pragma unroll
            for (int r = 0; r < 4; ++r) acc[t][r] *= alp[r];
        }
        #pragma unroll
        for (int r = 0; r < 4; ++r) acc_l[r] *= alp[r];

        // ---- P: C/D layout -> A layout via per-wave LDS round-trip
        hv8 pf0 = *reinterpret_cast<const hv8*>(&p_lds[wave][l15*72 + quad*8]);
        hv8 pf1 = *reinterpret_cast<const hv8*>(&p_lds[wave][l15*72 + 32 + quad*8]);

        // ---- O[q][co] += P V^T : 4 co-frags x 2 key-halves
        #pragma unroll
        for (int t = 0; t < 4; ++t) {
            hv8 d0 = *reinterpret_cast<const hv8*>(&dv_lds[(t*16 + l15)*72 + quad*8]);
            acc[t] = __builtin_amdgcn_mfma_f32_16x16x32_f16(pf0, d0, acc[t], 0, 0, 0);
            hv8 d1 = *reinterpret_cast<const hv8*>(&dv_lds[(t*16 + l15)*72 + 32 + quad*8]);
            acc[t] = __builtin_amdgcn_mfma_f32_16x16x32_f16(pf1, d1, acc[t], 0, 0, 0);
        }
        // ---- l[q] += rowsum(P) via ones-column MFMA
        acc_l = __builtin_amdgcn_mfma_f32_16x16x32_f16(pf0, ones, acc_l, 0, 0, 0);
        acc_l = __builtin_amdgcn_mfma_f32_16x16x32_f16(pf1, ones, acc_l, 0, 0, 0);
    }

    // ---- epilogue: out = alpha * O/l + a, transposed to [co][q] via LDS
    const float alpha = alpha_p[0];
    float rl[4];
    #pragma unroll
    for (int r = 0; r < 4; ++r) rl[r] = alpha / acc_l[r];

    __syncthreads();
    #pragma unroll
    for (int t = 0; t < 4; ++t) {
        #pragma unroll
        for (int r = 0; r < 4; ++r)
            trans[(t*16 + l15)*68 + wave*16 + quad*4 + r] = acc[t][r] * rl[r];
    }
    __syncthreads();
    #pragma unroll
    for (int it = 0; it < 4; ++it) {
        int row = it*16 + (tid >> 4);
        int col = (tid & 15) << 2;
        int co  = co0 + row;
        float4 v  = *reinterpret_cast<const float4*>(&trans[row*68 + col]);
        float4 av = *reinterpret_cast<const float4*>(
            a + ((size_t)n*CCH + co)*NHW + q0 + col);
        float4 o;
        o.x = v.x + av.x; o.y = v.y + av.y; o.z = v.z + av.z; o.w = v.w + av.w;
        *reinterpret_cast<float4*>(out + ((size_t)n*CCH + co)*NHW + q0 + col) = o;
    }
}

extern "C" void kernel_launch(void* const* d_in, const int* in_sizes, int n_in,
                              void* d_out, int out_size, void* d_ws, size_t ws_size,
                              hipStream_t stream)
{
    const float* a    = (const float*)d_in[0];
    const float* b_w  = (const float*)d_in[1];
    const float* b_b  = (const float*)d_in[2];
    const float* c_w  = (const float*)d_in[3];
    const float* c_b  = (const float*)d_in[4];
    const float* d_w  = (const float*)d_in[5];
    const float* d_b  = (const float*)d_in[6];
    const float* alp  = (const float*)d_in[7];
    float* out = (float*)d_out;

    _Float16* bqT = (_Float16*)d_ws;                  // [4][4096][32] fp16, 1 MB
    _Float16* ckT = bqT + (size_t)4*NHW*CQK;          // [4][4096][32] fp16, 1 MB
    _Float16* dv  = ckT + (size_t)4*NHW*CQK;          // [4][256][4096] fp16, 8 MB

    proj_kernel<<<512, 256, 0, stream>>>(a, b_w, b_b, c_w, c_b, d_w, d_b, bqT, ckT, dv);
    attn_kernel<<<1024, 256, 0, stream>>>(bqT, ckT, dv, a, alp, out);
}

// Round 5
// 232.898 us; speedup vs baseline: 2.4303x; 1.2583x over previous
//
#include <hip/hip_runtime.h>
#include <hip/hip_bf16.h>

#define CCH 256
#define CQK 32
#define NHW 4096

typedef float f32x4 __attribute__((ext_vector_type(4)));
typedef _Float16 hv8 __attribute__((ext_vector_type(8)));

// Monotone float<->uint encoding so float max == uint max (handles negatives).
__device__ __forceinline__ unsigned enc_f32(float f) {
    unsigned u = __float_as_uint(f);
    return (u & 0x80000000u) ? ~u : (u | 0x80000000u);
}
__device__ __forceinline__ float dec_f32(unsigned u) {
    return __uint_as_float((u & 0x80000000u) ? (u ^ 0x80000000u) : ~u);
}

// ---------------------------------------------------------------------------
// Prep kernel: (a) convert Wall = concat(b_w, c_w, d_w) fp32 -> fp16 [320][256]
// (removes the 128x-redundant per-tile conversion in proj); (b) init m_enc = 0
// (= encoded very-negative float; every row gets >= one atomicMax update).
// Grid 144 x 256: blocks 0..79 convert (4 elems/thread), 80..143 init m_enc.
// ---------------------------------------------------------------------------
__global__ __launch_bounds__(256) void prep_kernel(
    const float* __restrict__ b_w, const float* __restrict__ c_w,
    const float* __restrict__ d_w, _Float16* __restrict__ Wh,
    unsigned* __restrict__ m_enc)
{
    const int bid = blockIdx.x, tid = threadIdx.x;
    if (bid < 80) {
        const int idx = (bid * 256 + tid) * 4;     // multiple of 4, < 81920
        const int row = idx >> 8, col = idx & 255;
        const float* src = (row < 32) ? (b_w + row * CCH + col)
                         : (row < 64) ? (c_w + (row - 32) * CCH + col)
                                      : (d_w + (row - 64) * CCH + col);
        float4 v = *reinterpret_cast<const float4*>(src);
        _Float16* dst = Wh + (size_t)row * CCH + col;
        dst[0] = (_Float16)v.x; dst[1] = (_Float16)v.y;
        dst[2] = (_Float16)v.z; dst[3] = (_Float16)v.w;
    } else {
        m_enc[(bid - 80) * 256 + tid] = 0u;
    }
}

// ---------------------------------------------------------------------------
// Projection kernel (round-4 verified structure; W now pre-converted fp16).
// Grid: 4 batches x 128 position-tiles of 32. Block 256 = 4 waves; wave w owns
// out-channels 80w..80w+79 (5 m-frags) x 32 positions (2 n-frags).
// LDS row stride 280 halves = 560 B (16B-aligned for ds_read_b128; 140 dwords
// = 12 mod 32 banks -> 2-way max, free).
// ---------------------------------------------------------------------------
__global__ __launch_bounds__(256) void proj_kernel(
    const float* __restrict__ a, const _Float16* __restrict__ Wh,
    const float* __restrict__ b_b, const float* __restrict__ c_b,
    const float* __restrict__ d_b,
    _Float16* __restrict__ bqT, _Float16* __restrict__ ckT,
    _Float16* __restrict__ dv)
{
    __shared__ _Float16 aT[32][CCH + 24];   // [pos][ch] fp16, ~17.9 KB

    const int n    = blockIdx.x >> 7;
    const int i0   = (blockIdx.x & 127) << 5;
    const int tid  = threadIdx.x;
    const int lane = tid & 63;
    const int wave = tid >> 6;
    const int l15  = lane & 15;
    const int quad = lane >> 4;

    // stage a^T tile: thread handles channel c = tid, 32 positions
    {
        const float* ap = a + (size_t)(n*CCH + tid)*NHW + i0;
        #pragma unroll
        for (int j = 0; j < 8; ++j) {
            float4 v = *reinterpret_cast<const float4*>(ap + j*4);
            aT[j*4+0][tid] = (_Float16)v.x;
            aT[j*4+1][tid] = (_Float16)v.y;
            aT[j*4+2][tid] = (_Float16)v.z;
            aT[j*4+3][tid] = (_Float16)v.w;
        }
    }
    __syncthreads();

    const f32x4 zf = {0.f, 0.f, 0.f, 0.f};
    f32x4 acc[5][2];
    #pragma unroll
    for (int t = 0; t < 5; ++t) { acc[t][0] = zf; acc[t][1] = zf; }

    const int ch0w = wave * 80;

    #pragma unroll
    for (int ks = 0; ks < 8; ++ks) {
        const int k0 = ks * 32;
        hv8 bf0 = *reinterpret_cast<const hv8*>(&aT[l15][k0 + quad*8]);
        hv8 bf1 = *reinterpret_cast<const hv8*>(&aT[16 + l15][k0 + quad*8]);
        #pragma unroll
        for (int t = 0; t < 5; ++t) {
            const int ch0 = ch0w + t*16;
            hv8 af = *reinterpret_cast<const hv8*>(
                Wh + (size_t)(ch0 + l15)*CCH + k0 + quad*8);
            acc[t][0] = __builtin_amdgcn_mfma_f32_16x16x32_f16(af, bf0, acc[t][0], 0, 0, 0);
            acc[t][1] = __builtin_amdgcn_mfma_f32_16x16x32_f16(af, bf1, acc[t][1], 0, 0, 0);
        }
    }

    // epilogue: C/D layout row = quad*4+r (out-ch), col = l15 (pos)
    #pragma unroll
    for (int t = 0; t < 5; ++t) {
        const int ch0 = ch0w + t*16;
        if (ch0 < 64) {
            const float* bias_arr = (ch0 < 32) ? b_b : c_b;
            _Float16*    outp     = (ch0 < 32) ? bqT : ckT;
            const int    chl      = ch0 & 31;
            #pragma unroll
            for (int r = 0; r < 4; ++r) {
                const int ch_in = chl + quad*4 + r;
                const float bias = bias_arr[ch_in];
                #pragma unroll
                for (int nf = 0; nf < 2; ++nf) {
                    const int pos = i0 + nf*16 + l15;
                    outp[((size_t)n*NHW + pos)*CQK + ch_in] =
                        (_Float16)(acc[t][nf][r] + bias);
                }
            }
        } else {
            const int chd = ch0 - 64;
            #pragma unroll
            for (int r = 0; r < 4; ++r) {
                const int ch = chd + quad*4 + r;
                const float bias = d_b[ch];
                #pragma unroll
                for (int nf = 0; nf < 2; ++nf) {
                    const int pos = i0 + nf*16 + l15;
                    dv[((size_t)n*CCH + ch)*NHW + pos] =
                        (_Float16)(acc[t][nf][r] + bias);
                }
            }
        }
    }
}

// ---------------------------------------------------------------------------
// Pass A: per-q-row max of S = Q K^T (exact same fp16 MFMA products as pass B,
// so exp(s - m) <= 1 exactly). Grid: 4n x 64qt x 4 k-splits = 1024 blocks.
// Each wave: its 16 q-rows over 1024 keys; block-local max then atomicMax
// (uint-encoded) into m_enc[n][q].
// ---------------------------------------------------------------------------
__global__ __launch_bounds__(256) void rowmax_kernel(
    const _Float16* __restrict__ bqT, const _Float16* __restrict__ ckT,
    unsigned* __restrict__ m_enc)
{
    const int bx   = blockIdx.x;
    const int n    = bx >> 8;
    const int qt   = (bx >> 2) & 63;
    const int ks   = bx & 3;
    const int q0   = qt << 6;
    const int tid  = threadIdx.x;
    const int wave = tid >> 6;
    const int lane = tid & 63;
    const int l15  = lane & 15;
    const int quad = lane >> 4;

    const f32x4 zf = {0.f, 0.f, 0.f, 0.f};
    const hv8 qf = *reinterpret_cast<const hv8*>(
        bqT + ((size_t)n*NHW + q0 + wave*16 + l15)*CQK + quad*8);

    float mx[4] = {-1e30f, -1e30f, -1e30f, -1e30f};

    for (int kt = ks*16; kt < ks*16 + 16; ++kt) {
        const int k0 = kt << 6;
        f32x4 s[4];
        #pragma unroll
        for (int f = 0; f < 4; ++f) {
            hv8 kf = *reinterpret_cast<const hv8*>(
                ckT + ((size_t)n*NHW + k0 + f*16 + l15)*CQK + quad*8);
            s[f] = __builtin_amdgcn_mfma_f32_16x16x32_f16(qf, kf, zf, 0, 0, 0);
        }
        #pragma unroll
        for (int r = 0; r < 4; ++r)
            mx[r] = fmaxf(mx[r], fmaxf(fmaxf(s[0][r], s[1][r]),
                                        fmaxf(s[2][r], s[3][r])));
    }
    #pragma unroll
    for (int r = 0; r < 4; ++r) {
        float v = mx[r];
        v = fmaxf(v, __shfl_xor(v, 1, 64));
        v = fmaxf(v, __shfl_xor(v, 2, 64));
        v = fmaxf(v, __shfl_xor(v, 4, 64));
        v = fmaxf(v, __shfl_xor(v, 8, 64));
        mx[r] = v;
    }
    if (l15 == 0) {
        #pragma unroll
        for (int r = 0; r < 4; ++r)
            atomicMax(&m_enc[n*NHW + q0 + wave*16 + quad*4 + r], enc_f32(mx[r]));
    }
}

// ---------------------------------------------------------------------------
// Pass B: flash attention with PRE-COMPUTED row max — no online rescaling:
// no per-iter max reduce, no alp, no accumulator rescale. Round-4 verified
// MFMA layouts and staging, deletions only. Denominator via ones-column MFMA.
// Grid: 4n x 4 co-groups x 64 q-tiles = 1024.
// ---------------------------------------------------------------------------
__global__ __launch_bounds__(256) void attn_kernel(
    const _Float16* __restrict__ bqT, const _Float16* __restrict__ ckT,
    const _Float16* __restrict__ dv, const unsigned* __restrict__ m_enc,
    const float* __restrict__ a, const float* __restrict__ alpha_p,
    float* __restrict__ out)
{
    __shared__ _Float16 dv_lds[64 * 72];     // V tile [64co][64k]+8 pad
    __shared__ _Float16 p_lds[4][16 * 72];   // per-wave P round-trip
    __shared__ float    trans[64 * 68];      // epilogue transpose

    const int bx   = blockIdx.x;
    const int n    = bx >> 8;
    const int cg   = (bx >> 6) & 3;
    const int q0   = (bx & 63) << 6;
    const int co0  = cg << 6;
    const int tid  = threadIdx.x;
    const int wave = tid >> 6;
    const int lane = tid & 63;
    const int l15  = lane & 15;
    const int quad = lane >> 4;

    const f32x4 zf = {0.f, 0.f, 0.f, 0.f};
    const _Float16 one_h = (_Float16)1.0f;
    const hv8 ones = { one_h, one_h, one_h, one_h, one_h, one_h, one_h, one_h };

    const hv8 qf = *reinterpret_cast<const hv8*>(
        bqT + ((size_t)n*NHW + q0 + wave*16 + l15)*CQK + quad*8);

    // fixed per-row max (exact: pass A maxed the same MFMA products)
    float m_r[4];
    #pragma unroll
    for (int r = 0; r < 4; ++r)
        m_r[r] = dec_f32(m_enc[n*NHW + q0 + wave*16 + quad*4 + r]);

    f32x4 acc[4];
    #pragma unroll
    for (int t = 0; t < 4; ++t) acc[t] = zf;
    f32x4 acc_l = zf;                       // softmax denominator per q-row

    const int co_s = tid >> 3;          // 0..31
    const int c8_s = (tid & 7) << 3;    // 0..56

    for (int kt = 0; kt < 64; ++kt) {
        const int k0 = kt << 6;
        __syncthreads();   // previous iteration's dv_lds readers done
        #pragma unroll
        for (int p = 0; p < 2; ++p) {
            int co = co_s + (p << 5);
            *reinterpret_cast<int4*>(&dv_lds[co*72 + c8_s]) =
                *reinterpret_cast<const int4*>(
                    dv + ((size_t)n*CCH + co0 + co)*NHW + k0 + c8_s);
        }
        __syncthreads();

        // ---- S = Q K^T (C/D: row=quad*4+r -> q, col=l15 -> key)
        f32x4 s[4];
        #pragma unroll
        for (int f = 0; f < 4; ++f) {
            hv8 kf = *reinterpret_cast<const hv8*>(
                ckT + ((size_t)n*NHW + k0 + f*16 + l15)*CQK + quad*8);
            s[f] = __builtin_amdgcn_mfma_f32_16x16x32_f16(qf, kf, zf, 0, 0, 0);
        }

        // ---- p = exp(s - m), fixed m: no online machinery
        #pragma unroll
        for (int f = 0; f < 4; ++f) {
            #pragma unroll
            for (int r = 0; r < 4; ++r) {
                float p = __expf(s[f][r] - m_r[r]);
                p_lds[wave][(quad*4 + r)*72 + f*16 + l15] = (_Float16)p;
            }
        }

        // ---- P: C/D layout -> A layout via per-wave LDS round-trip
        hv8 pf0 = *reinterpret_cast<const hv8*>(&p_lds[wave][l15*72 + quad*8]);
        hv8 pf1 = *reinterpret_cast<const hv8*>(&p_lds[wave][l15*72 + 32 + quad*8]);

        // ---- O[q][co] += P V^T : 4 co-frags x 2 key-halves
        #pragma unroll
        for (int t = 0; t < 4; ++t) {
            hv8 d0 = *reinterpret_cast<const hv8*>(&dv_lds[(t*16 + l15)*72 + quad*8]);
            acc[t] = __builtin_amdgcn_mfma_f32_16x16x32_f16(pf0, d0, acc[t], 0, 0, 0);
            hv8 d1 = *reinterpret_cast<const hv8*>(&dv_lds[(t*16 + l15)*72 + 32 + quad*8]);
            acc[t] = __builtin_amdgcn_mfma_f32_16x16x32_f16(pf1, d1, acc[t], 0, 0, 0);
        }
        // ---- l[q] += rowsum(P) via ones-column MFMA
        acc_l = __builtin_amdgcn_mfma_f32_16x16x32_f16(pf0, ones, acc_l, 0, 0, 0);
        acc_l = __builtin_amdgcn_mfma_f32_16x16x32_f16(pf1, ones, acc_l, 0, 0, 0);
    }

    // ---- epilogue: out = alpha * O/l + a, transposed to [co][q] via LDS
    const float alpha = alpha_p[0];
    float rl[4];
    #pragma unroll
    for (int r = 0; r < 4; ++r) rl[r] = alpha / acc_l[r];

    __syncthreads();
    #pragma unroll
    for (int t = 0; t < 4; ++t) {
        #pragma unroll
        for (int r = 0; r < 4; ++r)
            trans[(t*16 + l15)*68 + wave*16 + quad*4 + r] = acc[t][r] * rl[r];
    }
    __syncthreads();
    #pragma unroll
    for (int it = 0; it < 4; ++it) {
        int row = it*16 + (tid >> 4);
        int col = (tid & 15) << 2;
        int co  = co0 + row;
        float4 v  = *reinterpret_cast<const float4*>(&trans[row*68 + col]);
        float4 av = *reinterpret_cast<const float4*>(
            a + ((size_t)n*CCH + co)*NHW + q0 + col);
        float4 o;
        o.x = v.x + av.x; o.y = v.y + av.y; o.z = v.z + av.z; o.w = v.w + av.w;
        *reinterpret_cast<float4*>(out + ((size_t)n*CCH + co)*NHW + q0 + col) = o;
    }
}

extern "C" void kernel_launch(void* const* d_in, const int* in_sizes, int n_in,
                              void* d_out, int out_size, void* d_ws, size_t ws_size,
                              hipStream_t stream)
{
    const float* a    = (const float*)d_in[0];
    const float* b_w  = (const float*)d_in[1];
    const float* b_b  = (const float*)d_in[2];
    const float* c_w  = (const float*)d_in[3];
    const float* c_b  = (const float*)d_in[4];
    const float* d_w  = (const float*)d_in[5];
    const float* d_b  = (const float*)d_in[6];
    const float* alp  = (const float*)d_in[7];
    float* out = (float*)d_out;

    _Float16* bqT  = (_Float16*)d_ws;                 // [4][4096][32] fp16, 1 MB
    _Float16* ckT  = bqT + (size_t)4*NHW*CQK;         // [4][4096][32] fp16, 1 MB
    _Float16* dv   = ckT + (size_t)4*NHW*CQK;         // [4][256][4096] fp16, 8 MB
    unsigned* m_enc = (unsigned*)(dv + (size_t)4*CCH*NHW);  // [4][4096] u32, 64 KB
    _Float16* Wh   = (_Float16*)(m_enc + 4*NHW);      // [320][256] fp16, 160 KB

    prep_kernel<<<144, 256, 0, stream>>>(b_w, c_w, d_w, Wh, m_enc);
    proj_kernel<<<512, 256, 0, stream>>>(a, Wh, b_b, c_b, d_b, bqT, ckT, dv);
    rowmax_kernel<<<1024, 256, 0, stream>>>(bqT, ckT, m_enc);
    attn_kernel<<<1024, 256, 0, stream>>>(bqT, ckT, dv, m_enc, a, alp, out);
}